// Round 9
// baseline (156.446 us; speedup 1.0000x reference)
//
#include <hip/hip_runtime.h>
#include <stdint.h>

// Problem geometry (fixed by reference):
//   preds      [8, 21, 512, 512] f32
//   embeddings [8, 128, 128, 128] f32
//   gts        [8, 512, 512] i32  (unused)
//   fsss_gts   [8, 512, 512] i32
//   pos_memory [1000, 128] f32
//   neg_memory [1000, 128] f32
//   out: scalar f32
// Downsample 512->128 nearest picks rows/cols 4i, 4j exactly.
//
// Ledger of structural findings:
//  R3: cg grid.sync() ~60us/sync (cross-XCD) -> banned.
//  R4: owner-block selection (ballot + prefix) is the right selection shape.
//  R6: serial single-block flag-walk = ~125us -> selection stays with owners;
//      completion-counter + CHEAP finisher (KB-scale reads) costs only ~5us.
//  R7 vs R8 (same container A/B): NT loads on preds/fsss are ~11us FASTER
//      (harness fills thrash L3 between replays; no warmth to protect).
//  R4 vs R7/R8 deltas were cross-container noise - containers changed at R5/R6.
//  R9: single in-kernel barrier (counter + prefix-finisher + flag poll) fuses
//      mask+select into K1; flags array eliminated; 2 kernels + tiny memset.

#define NPOS  131072   // 8*128*128
#define NBLK  512      // NPOS / 256
#define MEMSZ 1000
#define KANC  100      // MEM/10
#define KPN   333      // MEM/3
#define SLOT_POS 100
#define SLOT_NEG 433
#define FIX_SCALE 1099511627776.0        // 2^40
#define INV_FIX   (1.0 / 1099511627776.0)

// ws byte layout
#define OFF_COUNTS  0          // 3*512*4 = 6144
#define OFF_PREFIX  6144       // 3*512*4 = 6144
#define OFF_IDX     12288      // 768*4   = 3072
#define OFF_TOTALS  15360      // 16
#define OFF_ACCUM   15376      // 4*3*128*8 = 12288 (8-aligned: 15376 = 8*1922)
#define OFF_CTRA    27664      // 4
#define OFF_CTRB    27668      // 4
#define OFF_FLAG    27672      // 4
#define ZERO_BASE   OFF_ACCUM
#define ZERO_BYTES  (12288 + 12)   // accum + ctrA + ctrB + flag

// ====== K1: mask (NT loads) + counts + in-kernel barrier + owner-block select ======
__global__ __launch_bounds__(256) void mask_select_kernel(
    const float* __restrict__ preds,
    const int* __restrict__ fsss,
    int* __restrict__ blockCounts,    // [3][512]
    int* __restrict__ prefixTab,      // [3][512] exclusive prefixes
    int* __restrict__ idx,            // 768
    int* __restrict__ totals,         // 4
    unsigned int* __restrict__ counterA,
    unsigned int* __restrict__ flagReady)
{
    const int tid = threadIdx.x, blk = blockIdx.x;
    const int lane = tid & 63, wave = tid >> 6;
    const int n = blk * 256 + tid;
    const int b = n >> 14;
    const int ij = n & 16383;
    const int row = (ij >> 7) << 2;
    const int col = (ij & 127) << 2;

    // ---- phase 1: argmax over 21 channels at sampled (row,col) ----
    const float* p = preds + (size_t)b * 21 * 262144 + (size_t)row * 512 + col;
    float best = __builtin_nontemporal_load(p);
    int bc = 0;
#pragma unroll
    for (int c = 1; c < 21; ++c) {
        float v = __builtin_nontemporal_load(p + (size_t)c * 262144);
        if (v > best) { best = v; bc = c; }   // strict > = first-max (jnp.argmax)
    }
    const int fv = __builtin_nontemporal_load(
        fsss + (size_t)b * 262144 + (size_t)row * 512 + col);

    const bool pm = (bc != 0);
    const bool fm = (fv != 0) && (fv != 255);
    const int myflag = (int)(pm && fm)                // bit0: anchor
                     | ((int)(!pm && fm) << 1)        // bit1: positive
                     | ((int)(pm && (fv == 0)) << 2); // bit2: negative

    __shared__ int s_i[32];
    __shared__ int s_w[4];
    __shared__ int s_pre[3 * NBLK];   // 6KB, used by finisher only
#pragma unroll
    for (int cat = 0; cat < 3; ++cat) {
        unsigned long long m = __ballot((myflag >> cat) & 1);
        if (lane == 0) s_i[cat * 4 + wave] = (int)__popcll(m);
    }
    __syncthreads();
    if (tid < 3)
        blockCounts[tid * NBLK + blk] =
            s_i[tid * 4] + s_i[tid * 4 + 1] + s_i[tid * 4 + 2] + s_i[tid * 4 + 3];

    // ---- barrier arrive: release writes, bump counter ----
    __threadfence();                  // wbL2: make counts visible device-wide
    __syncthreads();
    __shared__ int s_last;
    if (tid == 0) {
        unsigned old = atomicAdd(counterA, 1u);
        s_last = (old == NBLK - 1) ? 1 : 0;
    }
    __syncthreads();

    if (s_last) {
        // ---- finisher: acquire, scan 3x512 counts -> prefix table + totals ----
        __threadfence();              // inv: see all blocks' counts
#pragma unroll 1
        for (int cat = 0; cat < 3; ++cat) {
            const int c0 = blockCounts[cat * NBLK + 2 * tid];
            const int c1 = blockCounts[cat * NBLK + 2 * tid + 1];
            const int pairsum = c0 + c1;
            int incl = pairsum;
#pragma unroll
            for (int off = 1; off < 64; off <<= 1) {
                int v = __shfl_up(incl, off, 64);
                if (lane >= off) incl += v;
            }
            if (lane == 63) s_w[wave] = incl;
            __syncthreads();
            int woff = 0;
#pragma unroll
            for (int w = 0; w < 4; ++w) if (w < wave) woff += s_w[w];
            const int excl0 = woff + incl - pairsum;
            s_pre[cat * NBLK + 2 * tid]     = excl0;        // (kept for symmetry)
            s_pre[cat * NBLK + 2 * tid + 1] = excl0 + c0;
            prefixTab[cat * NBLK + 2 * tid]     = excl0;
            prefixTab[cat * NBLK + 2 * tid + 1] = excl0 + c0;
            if (tid == 0) totals[cat] = s_w[0] + s_w[1] + s_w[2] + s_w[3];
            __syncthreads();
        }
        __threadfence();              // release prefixTab + totals
        __syncthreads();
        if (tid == 0)
            __hip_atomic_store(flagReady, 1u, __ATOMIC_RELAXED,
                               __HIP_MEMORY_SCOPE_AGENT);
    }

    // ---- barrier wait: sleep-poll the flag (relaxed), then acquire ----
    if (tid == 0) {
        while (__hip_atomic_load(flagReady, __ATOMIC_RELAXED,
                                 __HIP_MEMORY_SCOPE_AGENT) == 0u)
            __builtin_amdgcn_s_sleep(16);
    }
    __syncthreads();
    __threadfence();                  // acquire: fresh prefixTab/totals
    __shared__ int s_pre3[3];
    if (tid == 0) {
#pragma unroll
        for (int cat = 0; cat < 3; ++cat)
            s_pre3[cat] = prefixTab[cat * NBLK + blk];
    }
    __syncthreads();

    // ---- owner-block first-k selection (myflag still in registers) ----
    unsigned long long masks[3];
#pragma unroll
    for (int cat = 0; cat < 3; ++cat) {
        masks[cat] = __ballot((myflag >> cat) & 1);
        if (lane == 0) s_i[cat * 4 + wave] = (int)__popcll(masks[cat]);
    }
    __syncthreads();
    const int kcap[3]  = {KANC, KPN, KPN};
    const int basec[3] = {0, SLOT_POS, SLOT_NEG};
#pragma unroll
    for (int cat = 0; cat < 3; ++cat) {
        if ((myflag >> cat) & 1) {
            int woff = 0;
#pragma unroll
            for (int w = 0; w < 4; ++w) if (w < wave) woff += s_i[cat * 4 + w];
            const int intra = woff + (int)__popcll(masks[cat] & ((1ull << lane) - 1ull));
            const int rank = s_pre3[cat] + intra;
            if (rank < kcap[cat]) idx[basec[cat] + rank] = n;
        }
    }
}

// ====== K2: gather+normalize -> fixed-point accum; cheap finisher does the dot ======
// blocks 0..382: 2 slots each.  blocks 383..398: untouched-memory-row tails.
__global__ __launch_bounds__(256) void gather_final_kernel(
    const float* __restrict__ emb,
    const float* __restrict__ posMem,
    const float* __restrict__ negMem,
    const int* __restrict__ idx,
    const int* __restrict__ totals,
    unsigned long long* __restrict__ accum,   // [4 shadows][3 cats][128]
    unsigned int* __restrict__ counterB,
    float* __restrict__ out)
{
    const int tid = threadIdx.x, blk = blockIdx.x;
    const int lane = tid & 63, wave = tid >> 6;
    const int d = tid & 127;
    const int A = min(KANC, totals[0]);
    const int P = min(KPN, totals[1]);
    const int Q = min(KPN, totals[2]);

    if (blk < 383) {
        const int half = tid >> 7;
        const int slot = blk * 2 + half;      // 0..765
        int cat; bool valid;
        if (slot < SLOT_POS)      { cat = 0; valid = slot < A; }
        else if (slot < SLOT_NEG) { cat = 1; valid = (slot - SLOT_POS) < P; }
        else                      { cat = 2; valid = (slot - SLOT_NEG) < Q; }

        float v = 0.f;
        if (valid) {
            const int nn = idx[slot];
            v = emb[((size_t)(nn >> 14) * 128 + d) * 16384 + (nn & 16383)];
        }
        float sq = v * v;
#pragma unroll
        for (int off = 1; off < 64; off <<= 1) sq += __shfl_xor(sq, off, 64);
        __shared__ float s_f[4];
        if (lane == 0) s_f[wave] = sq;
        __syncthreads();
        const float nrm2 = s_f[half * 2] + s_f[half * 2 + 1];
        if (valid) {
            const float scale = 1.0f / fmaxf(sqrtf(nrm2), 1e-12f);
            const long long fx =
                (long long)llrint((double)v * (double)scale * FIX_SCALE);
            atomicAdd(&accum[(((blk & 3) * 3 + cat) << 7) + d],
                      (unsigned long long)fx);
        }
    } else {
        const int t = blk - 383;
        const int memSel = t >> 3;            // 0=pos, 1=neg
        const int part = t & 7;
        const float* mem = memSel ? negMem : posMem;
        const int cnt = memSel ? Q : P;       // rows [0,cnt) replaced by selections
        const int rowHalf = tid >> 7;
        const int m0 = part * 125;
        double acc = 0.0;
        for (int r = rowHalf; r < 125; r += 2) {
            const int m = m0 + r;
            if (m >= cnt) acc += (double)mem[(size_t)m * 128 + d];
        }
        const long long fx = (long long)llrint(acc * FIX_SCALE);
        atomicAdd(&accum[(((blk & 3) * 3 + (memSel ? 2 : 1)) << 7) + d],
                  (unsigned long long)fx);
    }

    // ---- release, completion count (cheap-finisher pattern, proven R6-R8) ----
    __threadfence();
    __syncthreads();
    __shared__ int s_fin;
    if (tid == 0) {
        unsigned old = atomicAdd(counterB, 1u);
        s_fin = (old == 398) ? 1 : 0;
    }
    __syncthreads();
    if (!s_fin) return;
    __threadfence();

    // ---- finisher: final dot + relu (reads only 12KB accum) ----
    __shared__ double s_d[2];
    if (tid < 128) {
        double anc = 0.0, pos = 0.0, neg = 0.0;
#pragma unroll
        for (int s = 0; s < 4; ++s) {
            anc += (double)(long long)accum[((s * 3 + 0) << 7) + tid];
            pos += (double)(long long)accum[((s * 3 + 1) << 7) + tid];
            neg += (double)(long long)accum[((s * 3 + 2) << 7) + tid];
        }
        double prod = anc * (pos - neg) * (INV_FIX * INV_FIX);
#pragma unroll
        for (int off = 1; off < 64; off <<= 1) prod += __shfl_xor(prod, off, 64);
        if (lane == 0) s_d[wave] = prod;
    }
    __syncthreads();
    if (tid == 0) {
        const double red = s_d[0] + s_d[1];
        const double nAnc = (A > 0) ? (double)A : 1.0;
        const double vv = red / (nAnc * (double)MEMSZ) + 0.2;
        out[0] = (float)(vv > 0.0 ? vv : 0.0);
    }
}

extern "C" void kernel_launch(void* const* d_in, const int* in_sizes, int n_in,
                              void* d_out, int out_size, void* d_ws, size_t ws_size,
                              hipStream_t stream) {
    const float* preds  = (const float*)d_in[0];
    const float* emb    = (const float*)d_in[1];
    // d_in[2] = gts, unused by the loss
    const int* fsss     = (const int*)d_in[3];
    const float* posMem = (const float*)d_in[4];
    const float* negMem = (const float*)d_in[5];
    float* out = (float*)d_out;

    char* ws = (char*)d_ws;
    int* blockCounts    = (int*)(ws + OFF_COUNTS);
    int* prefixTab      = (int*)(ws + OFF_PREFIX);
    int* idx            = (int*)(ws + OFF_IDX);
    int* totals         = (int*)(ws + OFF_TOTALS);
    unsigned long long* accum = (unsigned long long*)(ws + OFF_ACCUM);
    unsigned int* ctrA  = (unsigned int*)(ws + OFF_CTRA);
    unsigned int* ctrB  = (unsigned int*)(ws + OFF_CTRB);
    unsigned int* flag  = (unsigned int*)(ws + OFF_FLAG);

    // zero accum + counters + barrier flag every replay (ws not re-poisoned)
    hipMemsetAsync(ws + ZERO_BASE, 0, ZERO_BYTES, stream);

    mask_select_kernel<<<NBLK, 256, 0, stream>>>(preds, fsss, blockCounts,
                                                 prefixTab, idx, totals,
                                                 ctrA, flag);
    gather_final_kernel<<<399, 256, 0, stream>>>(emb, posMem, negMem, idx, totals,
                                                 accum, ctrB, out);
}

// Round 10
// 49.113 us; speedup vs baseline: 3.1854x; 3.1854x over previous
//
#include <hip/hip_runtime.h>
#include <stdint.h>

// Problem geometry (fixed by reference):
//   preds      [8, 21, 512, 512] f32
//   embeddings [8, 128, 128, 128] f32
//   gts        [8, 512, 512] i32  (unused)
//   fsss_gts   [8, 512, 512] i32
//   pos_memory [1000, 128] f32
//   neg_memory [1000, 128] f32
//   out: scalar f32
// Downsample 512->128 nearest picks rows/cols 4i, 4j exactly.
//
// Ledger of structural findings:
//  R3/R9: ANY device-wide barrier where blocks WAIT (cg grid.sync OR
//      counter+flag-poll) costs >100us on MI355X (warm replays of R9 were
//      still ~140us with FETCH=0.08MB). Fire-and-forget completion-counter
//      finisher (non-finishers EXIT) costs ~5us -> only allowed pattern.
//  R4: owner-block selection (ballot + redundant prefix) is the right shape.
//  R6: serial single-block flag-walk = ~125us -> never serial global walks.
//  R7 vs R8 (same-container A/B): NT loads on preds/fsss ~11us faster
//      (harness fills thrash L3 between replays; no warmth to protect).
//  Cross-container deltas (R4 vs R7) are noise; containers changed R5/R6.
//  R10: kill the select dispatch with NO barrier: gather blocks recompute the
//      prefix table redundantly (6KB scan ~1us) and INVERT the first-k map for
//      their own <=2 slots (binsearch + ballot-rank on 256 flag bytes).
//      2 dispatches, 1 boundary, no idx/totals buffers, no memset node.

#define NPOS  131072   // 8*128*128
#define NBLK  512      // NPOS / 256
#define MEMSZ 1000
#define KANC  100      // MEM/10
#define KPN   333      // MEM/3
#define SLOT_POS 100
#define SLOT_NEG 433
#define FIX_SCALE 1099511627776.0        // 2^40
#define INV_FIX   (1.0 / 1099511627776.0)

// ws byte layout
#define OFF_FLAGS   0          // 131072 B
#define OFF_COUNTS  131072     // 3*512*4 = 6144 B
#define OFF_ACCUM   137216     // 4*3*128*8 = 12288 B (8-aligned)
#define OFF_CTR     149504     // 4 B

// ========= K1: argmax + masks + flags + per-block counts; block 0 zeroes =========
__global__ __launch_bounds__(256) void mask_kernel(
    const float* __restrict__ preds,
    const int* __restrict__ fsss,
    uint8_t* __restrict__ flags,
    int* __restrict__ blockCounts,
    unsigned long long* __restrict__ accum,
    unsigned int* __restrict__ counterB)
{
    const int tid = threadIdx.x, blk = blockIdx.x;
    const int lane = tid & 63, wave = tid >> 6;
    const int n = blk * 256 + tid;
    const int b = n >> 14;
    const int ij = n & 16383;
    const int row = (ij >> 7) << 2;
    const int col = (ij & 127) << 2;

    const float* p = preds + (size_t)b * 21 * 262144 + (size_t)row * 512 + col;
    float best = __builtin_nontemporal_load(p);
    int bc = 0;
#pragma unroll
    for (int c = 1; c < 21; ++c) {
        float v = __builtin_nontemporal_load(p + (size_t)c * 262144);
        if (v > best) { best = v; bc = c; }   // strict > = first-max (jnp.argmax)
    }
    const int fv = __builtin_nontemporal_load(
        fsss + (size_t)b * 262144 + (size_t)row * 512 + col);

    const bool pm = (bc != 0);
    const bool fm = (fv != 0) && (fv != 255);
    const int myflag = (int)(pm && fm)                // bit0: anchor
                     | ((int)(!pm && fm) << 1)        // bit1: positive
                     | ((int)(pm && (fv == 0)) << 2); // bit2: negative
    flags[n] = (uint8_t)myflag;

    __shared__ int s_i[12];
#pragma unroll
    for (int cat = 0; cat < 3; ++cat) {
        unsigned long long m = __ballot((myflag >> cat) & 1);
        if (lane == 0) s_i[cat * 4 + wave] = (int)__popcll(m);
    }
    __syncthreads();
    if (tid < 3)
        blockCounts[tid * NBLK + blk] =
            s_i[tid * 4] + s_i[tid * 4 + 1] + s_i[tid * 4 + 2] + s_i[tid * 4 + 3];

    // zero accum + K2's completion counter every replay (K2 runs after K1)
    if (blk == 0) {
        for (int i = tid; i < 4 * 3 * 128; i += 256) accum[i] = 0ull;
        if (tid == 0) *counterB = 0u;
    }
}

// ====== K2: redundant prefix scan + slot inversion + gather + cheap finisher ======
// blocks 0..382: 2 slots each.  blocks 383..398: untouched-memory-row tails.
__global__ __launch_bounds__(256) void select_gather_final_kernel(
    const float* __restrict__ emb,
    const float* __restrict__ posMem,
    const float* __restrict__ negMem,
    const uint8_t* __restrict__ flags,
    const int* __restrict__ blockCounts,
    unsigned long long* __restrict__ accum,   // [4 shadows][3 cats][128]
    unsigned int* __restrict__ counterB,
    float* __restrict__ out)
{
    const int tid = threadIdx.x, blk = blockIdx.x;
    const int lane = tid & 63, wave = tid >> 6;

    // ---- full exclusive prefix over [3][512] counts, redundant per block ----
    __shared__ int s_pre[3 * NBLK];   // 6 KB
    __shared__ int s_tot[3];
    __shared__ int s_w[4];
#pragma unroll 1
    for (int cat = 0; cat < 3; ++cat) {
        const int c0 = blockCounts[cat * NBLK + 2 * tid];
        const int c1 = blockCounts[cat * NBLK + 2 * tid + 1];
        const int pairsum = c0 + c1;
        int incl = pairsum;
#pragma unroll
        for (int off = 1; off < 64; off <<= 1) {
            int v = __shfl_up(incl, off, 64);
            if (lane >= off) incl += v;
        }
        if (lane == 63) s_w[wave] = incl;
        __syncthreads();
        int woff = 0;
#pragma unroll
        for (int w = 0; w < 4; ++w) if (w < wave) woff += s_w[w];
        const int excl0 = woff + incl - pairsum;
        s_pre[cat * NBLK + 2 * tid]     = excl0;
        s_pre[cat * NBLK + 2 * tid + 1] = excl0 + c0;
        if (tid == 0) s_tot[cat] = s_w[0] + s_w[1] + s_w[2] + s_w[3];
        __syncthreads();
    }
    const int A = min(KANC, s_tot[0]);
    const int P = min(KPN, s_tot[1]);
    const int Q = min(KPN, s_tot[2]);
    const int d = tid & 127;

    if (blk < 383) {
        // ---- invert the first-k map for this block's two slots ----
        __shared__ int s_nn[2];
        int nnv[2];   // resolved position per half, -1 if invalid slot
#pragma unroll 1
        for (int h = 0; h < 2; ++h) {
            const int slot = blk * 2 + h;
            int cat, r;
            if (slot < SLOT_POS)      { cat = 0; r = slot; }
            else if (slot < SLOT_NEG) { cat = 1; r = slot - SLOT_POS; }
            else                      { cat = 2; r = slot - SLOT_NEG; }
            const int cnt = (cat == 0) ? A : ((cat == 1) ? P : Q);
            if (r < cnt) {            // block-uniform branch
                // owner block: largest bb with pre[cat][bb] <= r  (redundant/thread)
                int lo = 0, hi = NBLK - 1;
                while (lo < hi) {
                    const int mid = (lo + hi + 1) >> 1;
                    if (s_pre[cat * NBLK + mid] <= r) lo = mid; else hi = mid - 1;
                }
                const int bb = lo;
                const int lr = r - s_pre[cat * NBLK + bb];
                // ballot-rank the owner's 256 flags to find intra-rank lr
                const int bit = (flags[bb * 256 + tid] >> cat) & 1;
                const unsigned long long m = __ballot(bit);
                if (lane == 0) s_w[wave] = (int)__popcll(m);
                __syncthreads();
                int woff = 0;
#pragma unroll
                for (int w = 0; w < 4; ++w) if (w < wave) woff += s_w[w];
                const int intra = woff + (int)__popcll(m & ((1ull << lane) - 1ull));
                if (bit && intra == lr) s_nn[h] = bb * 256 + tid;
                __syncthreads();
                nnv[h] = s_nn[h];
            } else {
                nnv[h] = -1;
            }
        }

        // ---- gather + normalize both slots (half per slot, R7-K3 shape) ----
        const int half = tid >> 7;
        const int slot = blk * 2 + half;
        const int cat = (slot < SLOT_POS) ? 0 : ((slot < SLOT_NEG) ? 1 : 2);
        const int nn = nnv[half];
        float v = 0.f;
        if (nn >= 0)
            v = emb[((size_t)(nn >> 14) * 128 + d) * 16384 + (nn & 16383)];
        float sq = v * v;
#pragma unroll
        for (int off = 1; off < 64; off <<= 1) sq += __shfl_xor(sq, off, 64);
        __shared__ float s_f[4];
        if (lane == 0) s_f[wave] = sq;   // waves 0,1 = half0; waves 2,3 = half1
        __syncthreads();
        const float nrm2 = s_f[half * 2] + s_f[half * 2 + 1];
        if (nn >= 0) {
            const float scale = 1.0f / fmaxf(sqrtf(nrm2), 1e-12f);
            const long long fx =
                (long long)llrint((double)v * (double)scale * FIX_SCALE);
            atomicAdd(&accum[(((blk & 3) * 3 + cat) << 7) + d],
                      (unsigned long long)fx);
        }
    } else {
        // ---- untouched-memory-row tails ----
        const int t = blk - 383;
        const int memSel = t >> 3;            // 0=pos, 1=neg
        const int part = t & 7;
        const float* mem = memSel ? negMem : posMem;
        const int cnt = memSel ? Q : P;       // rows [0,cnt) replaced by selections
        const int rowHalf = tid >> 7;
        const int m0 = part * 125;
        double acc = 0.0;
        for (int r = rowHalf; r < 125; r += 2) {
            const int m = m0 + r;
            if (m >= cnt) acc += (double)mem[(size_t)m * 128 + d];
        }
        const long long fx = (long long)llrint(acc * FIX_SCALE);
        atomicAdd(&accum[(((blk & 3) * 3 + (memSel ? 2 : 1)) << 7) + d],
                  (unsigned long long)fx);
    }

    // ---- release, completion count (fire-and-forget finisher, proven R6-R8) ----
    __threadfence();
    __syncthreads();
    __shared__ int s_fin;
    if (tid == 0) {
        unsigned old = atomicAdd(counterB, 1u);
        s_fin = (old == 398) ? 1 : 0;
    }
    __syncthreads();
    if (!s_fin) return;
    __threadfence();

    // ---- finisher: final dot + relu (reads only 12KB accum) ----
    __shared__ double s_d[2];
    if (tid < 128) {
        double anc = 0.0, pos = 0.0, neg = 0.0;
#pragma unroll
        for (int s = 0; s < 4; ++s) {
            anc += (double)(long long)accum[((s * 3 + 0) << 7) + tid];
            pos += (double)(long long)accum[((s * 3 + 1) << 7) + tid];
            neg += (double)(long long)accum[((s * 3 + 2) << 7) + tid];
        }
        double prod = anc * (pos - neg) * (INV_FIX * INV_FIX);
#pragma unroll
        for (int off = 1; off < 64; off <<= 1) prod += __shfl_xor(prod, off, 64);
        if (lane == 0) s_d[wave] = prod;
    }
    __syncthreads();
    if (tid == 0) {
        const double red = s_d[0] + s_d[1];
        const double nAnc = (A > 0) ? (double)A : 1.0;
        const double vv = red / (nAnc * (double)MEMSZ) + 0.2;
        out[0] = (float)(vv > 0.0 ? vv : 0.0);
    }
}

extern "C" void kernel_launch(void* const* d_in, const int* in_sizes, int n_in,
                              void* d_out, int out_size, void* d_ws, size_t ws_size,
                              hipStream_t stream) {
    const float* preds  = (const float*)d_in[0];
    const float* emb    = (const float*)d_in[1];
    // d_in[2] = gts, unused by the loss
    const int* fsss     = (const int*)d_in[3];
    const float* posMem = (const float*)d_in[4];
    const float* negMem = (const float*)d_in[5];
    float* out = (float*)d_out;

    char* ws = (char*)d_ws;
    uint8_t* flags      = (uint8_t*)(ws + OFF_FLAGS);
    int* blockCounts    = (int*)(ws + OFF_COUNTS);
    unsigned long long* accum = (unsigned long long*)(ws + OFF_ACCUM);
    unsigned int* ctr   = (unsigned int*)(ws + OFF_CTR);

    mask_kernel<<<NBLK, 256, 0, stream>>>(preds, fsss, flags, blockCounts,
                                          accum, ctr);
    select_gather_final_kernel<<<399, 256, 0, stream>>>(emb, posMem, negMem,
                                                        flags, blockCounts,
                                                        accum, ctr, out);
}